// Round 13
// baseline (4182.827 us; speedup 1.0000x reference)
//
#include <hip/hip_runtime.h>
#include <hip/hip_bf16.h>

// LSTM: B=256, T=512, D=512, H=512, fp32 in/out, fp16 compute (fp32 accum).
//   r18 = r15 scan (proven; r17's LDS-dedup regressed: h-loads were latency-free across
//   waves, dedup added a serial LDS hop + barrier -> reverted) + xg-GEMM fused into the
//   scan with r16's failure mode fixed:
//     r16 autopsy: tail had 48 compiler-serialized global loads (112 free VGPRs; L2/HBM
//     latency exposed serially) -> +14k cyc/step. Fixes here:
//       (1) Wx slice staged ONCE into 128KB DYNAMIC LDS (hipFuncSetAttribute +
//           sharedMemBytes on the cooperative launch; rc-checked). Tail reads are
//           ds_read_b128 (~12cyc, lgkmcnt-pipelined), not 32 L2 round trips.
//       (2) x fragments prefetched ONE FULL STEP ahead into registers (64 VGPR;
//           total ~280 < 512 at launch_bounds(256,1)).
//       (3) tail sits AFTER the h-publish -> off the inter-block critical path,
//           overlapped with wave 0's 2-4k cyc flag poll.
//     All loads compiler-tracked (r13/r16 lesson): h via r5-proven __hip_atomic_load
//     8B agent-scope; x plain loads; Wx via LDS. Only stores are inline asm.
//   RUNTIME FALLBACK: if set-attribute or cooperative launch fails -> r15-proven
//   k_gemm_xg + k_scan4 split path (worst case = r15 perf, never a wrong answer).
//   Deletes (fused path): k_gemm_xg dispatch, 512MB xg write + 341MB xg read.
//   Flag protocol per step (proven r10/r15): single-wave poll of 15 remote flags ->
//   barrier -> h loads -> recurrent MFMAs (C-in = fused xga) -> gates -> 16B/lane
//   sc0sc1 h store -> vmcnt(0) ack -> LDS-aggregated single flag store -> xg tail.

typedef _Float16 half8 __attribute__((ext_vector_type(8)));
typedef _Float16 half4 __attribute__((ext_vector_type(4)));
typedef int int4v __attribute__((ext_vector_type(4)));
typedef float float4v __attribute__((ext_vector_type(4)));

__device__ __forceinline__ void gl_lds16(const void* g, void* l) {
  __builtin_amdgcn_global_load_lds(
      (const __attribute__((address_space(1))) unsigned int*)g,
      (__attribute__((address_space(3))) unsigned int*)l, 16, 0, 0);
}

__device__ __forceinline__ float sigm(float v) { return 1.f / (1.f + __expf(-v)); }
__device__ __forceinline__ float tanh_(float v) { return 1.f - 2.f / (__expf(2.f * v) + 1.f); }

// ---------------------------------------------------------------- k_prep (x cast + bias)
__global__ __launch_bounds__(256) void k_prep(
    const float* __restrict__ x, const float* __restrict__ b,
    _Float16* __restrict__ xf, float* __restrict__ bp)
{
  const long NX8 = 67108864L / 8;
  const long TOT = NX8 + 2048;
  long stride = (long)gridDim.x * blockDim.x;
  for (long id = (long)blockIdx.x * blockDim.x + threadIdx.x; id < TOT; id += stride) {
    if (id < NX8) {
      const float4v* p = (const float4v*)x + id * 2;
      float4v a = p[0], c = p[1];
      half8 o;
      o[0]=(_Float16)a[0]; o[1]=(_Float16)a[1]; o[2]=(_Float16)a[2]; o[3]=(_Float16)a[3];
      o[4]=(_Float16)c[0]; o[5]=(_Float16)c[1]; o[6]=(_Float16)c[2]; o[7]=(_Float16)c[3];
      ((half8*)xf)[id] = o;
    } else {
      int np = (int)(id - NX8);
      int j = np >> 2, gt = np & 3;               // n' = j*4 + gate
      bp[np] = b[gt * 512 + j];
    }
  }
}

// ---------------------------------------------------------------- k_wtr (weight transpose)
__global__ __launch_bounds__(256) void k_wtr(
    const float* __restrict__ W, _Float16* __restrict__ Wt)
{
  __shared__ float lds[64][65];
  const int bbk = blockIdx.x;
  const int kt = bbk & 7, nt = bbk >> 3;
  const int tx = threadIdx.x & 63, ty = threadIdx.x >> 6;
  #pragma unroll
  for (int r = 0; r < 16; ++r) {
    int kl = ty * 16 + r;
    lds[kl][tx] = W[(long)(kt * 64 + kl) * 2048 + nt * 64 + tx];
  }
  __syncthreads();
  #pragma unroll
  for (int r = 0; r < 16; ++r) {
    int nl = ty * 16 + r;
    int n = nt * 64 + nl;
    int j = n & 511, gt = n >> 9;
    int np = j * 4 + gt;
    Wt[(long)np * 512 + kt * 64 + tx] = (_Float16)lds[tx][nl];
  }
}

// ---------------------------------------------------------------- k_gemm_xg (FALLBACK)
__global__ __launch_bounds__(256, 2) void k_gemm_xg(
    const _Float16* __restrict__ xf, const _Float16* __restrict__ wxt,
    const float* __restrict__ bp, _Float16* __restrict__ xg)
{
  __shared__ _Float16 As[128 * 32];
  __shared__ _Float16 Bs[128 * 32];
  const int tid = threadIdx.x;
  const int w = tid >> 6, l = tid & 63;
  const int mt = blockIdx.x >> 4, nt = blockIdx.x & 15;
  const int qr = (w >> 1) * 64, qc = (w & 1) * 64;
  float4v acc[4][4];
  #pragma unroll
  for (int i = 0; i < 4; ++i)
    #pragma unroll
    for (int j = 0; j < 4; ++j) acc[i][j] = (float4v){0.f, 0.f, 0.f, 0.f};
  const int lr = l >> 2, lc = (l & 3) * 8;
  for (int kt = 0; kt < 16; ++kt) {
    __syncthreads();
    #pragma unroll
    for (int i = 0; i < 2; ++i) {
      int chunk = i * 4 + w;
      gl_lds16(xf + ((long)(mt * 128 + chunk * 16 + lr)) * 512 + kt * 32 + lc, As + chunk * 512);
      gl_lds16(wxt + ((long)(nt * 128 + chunk * 16 + lr)) * 512 + kt * 32 + lc, Bs + chunk * 512);
    }
    __syncthreads();
    half8 af[4], bf[4];
    #pragma unroll
    for (int mi = 0; mi < 4; ++mi)
      af[mi] = *(const half8*)(As + (qr + mi * 16 + (l & 15)) * 32 + (l >> 4) * 8);
    #pragma unroll
    for (int ni = 0; ni < 4; ++ni)
      bf[ni] = *(const half8*)(Bs + (qc + ni * 16 + (l & 15)) * 32 + (l >> 4) * 8);
    #pragma unroll
    for (int mi = 0; mi < 4; ++mi)
      #pragma unroll
      for (int ni = 0; ni < 4; ++ni)
        acc[mi][ni] = __builtin_amdgcn_mfma_f32_16x16x32_f16(af[mi], bf[ni], acc[mi][ni], 0, 0, 0);
  }
  #pragma unroll
  for (int ni = 0; ni < 4; ++ni) {
    int col = nt * 128 + qc + ni * 16 + (l & 15);
    float bias = bp[col];
    #pragma unroll
    for (int mi = 0; mi < 4; ++mi) {
      long R0 = (long)mt * 128 + qr + mi * 16 + (l >> 4) * 4;
      #pragma unroll
      for (int r = 0; r < 4; ++r)
        xg[(R0 + r) * 2048 + col] = (_Float16)(acc[mi][ni][r] + bias);
    }
  }
}

// ---------------------------------------------------------------- k_scanf2 (fused, LDS-Wx)
extern __shared__ _Float16 lwx[];   // dynamic: 128KB = [w4][e2][kk16][q4][m16][8 f16]
__global__ __launch_bounds__(256, 1) void k_scanf2(
    const _Float16* __restrict__ xf, const _Float16* __restrict__ wht,
    const _Float16* __restrict__ wxt, const float* __restrict__ bp,
    const float* __restrict__ wfc, const float* __restrict__ bfc,
    _Float16* __restrict__ hsl, unsigned int* __restrict__ flags,
    float* __restrict__ out)
{
  __shared__ unsigned int wctr;
  const int tid = threadIdx.x;
  if (tid == 0) wctr = 0;

  const int w = tid >> 6, l = tid & 63;
  const int q = l >> 4;
  const int m = l & 15;
  const int bb = blockIdx.x;
  const int slot = bb >> 3;
  const int g = (bb & 7) * 2 + (slot >> 4);
  const int s = slot & 15;

  // Wh A-fragments pinned in VGPRs (proven).
  int4v bw0[16], bw1[16];
  {
    const _Float16* b0 = wht + ((long)(s * 128 + (2 * w + 0) * 16 + m)) * 512 + q * 8;
    const _Float16* b1 = wht + ((long)(s * 128 + (2 * w + 1) * 16 + m)) * 512 + q * 8;
    #pragma unroll
    for (int kk = 0; kk < 16; ++kk) {
      bw0[kk] = *(const int4v*)(b0 + kk * 32);
      bw1[kk] = *(const int4v*)(b1 + kk * 32);
    }
    #pragma unroll
    for (int kk = 0; kk < 16; ++kk)
      asm volatile("" : "+v"(bw0[kk]), "+v"(bw1[kk]));
  }
  // Wx slice -> LDS, once (each thread writes its own 32x16B slots; 128KB/block).
  #pragma unroll
  for (int e = 0; e < 2; ++e)
    for (int kk = 0; kk < 16; ++kk) {
      const _Float16* src = wxt + ((long)(s * 128 + (2 * w + e) * 16 + m)) * 512 + kk * 32 + q * 8;
      int idx = ((((w * 2 + e) * 16 + kk) * 4 + q) * 16 + m) * 8;
      *(int4v*)&lwx[idx] = *(const int4v*)src;
    }
  __syncthreads();   // staging (and wctr init) visible
  const int lb0 = ((w * 2 + 0) * 16) * 512 + q * 128 + m * 8;  // + kk*512
  const int lb1 = ((w * 2 + 1) * 16) * 512 + q * 128 + m * 8;

  float c0 = 0.f, c1 = 0.f;
  const int j0 = s * 32 + 8 * w + q;
  const int j1 = s * 32 + 8 * w + 4 + q;
  const float wf0 = wfc[j0], wf1 = wfc[j1];
  const float4v bq0 = *(const float4v*)(bp + j0 * 4);
  const float4v bq1 = *(const float4v*)(bp + j1 * 4);
  unsigned int* fl = flags + g * 256;
  const _Float16* xrow = xf + ((long)(g * 16 + m)) * 512 * 512 + q * 8;  // x[b][t][d]
  const _Float16* hrg = hsl + (long)g * 8192 + q * 128 + m * 8;
  _Float16* hw = hsl + (long)(g * 16 + s) * 512 + w * 128 + m * 8;

  // prologue: xga for t=0 from LDS Wx + x_0.
  float4v xga0 = (float4v){0.f,0.f,0.f,0.f}, xga1 = xga0;
  #pragma unroll
  for (int kk = 0; kk < 16; ++kk) {
    int4v xv = *(const int4v*)(xrow + kk * 32);
    half8 wa0 = *(const half8*)&lwx[lb0 + kk * 512];
    half8 wa1 = *(const half8*)&lwx[lb1 + kk * 512];
    xga0 = __builtin_amdgcn_mfma_f32_16x16x32_f16(wa0, __builtin_bit_cast(half8, xv), xga0, 0, 0, 0);
    xga1 = __builtin_amdgcn_mfma_f32_16x16x32_f16(wa1, __builtin_bit_cast(half8, xv), xga1, 0, 0, 0);
  }

  for (int t = 0; t < 512; ++t) {
    const int pr = t & 1;
    // x frags for t+1, issued a FULL STEP early (consumed in the tail below).
    int4v xbr[16];
    if (t < 511) {
      const _Float16* xr = xrow + (long)(t + 1) * 512;
      #pragma unroll
      for (int kk = 0; kk < 16; ++kk) xbr[kk] = *(const int4v*)(xr + kk * 32);
    }
    if (t) {
      if (w == 0 && l < 16 && l != s) {
        unsigned int* p = fl + l * 16;
        while (__hip_atomic_load(p, __ATOMIC_RELAXED, __HIP_MEMORY_SCOPE_AGENT)
               < (unsigned)t) {}
      }
      asm volatile("" ::: "memory");
      __syncthreads();
    }
    // h loads: r5-proven compiler-tracked 8B agent-scope atomics.
    const _Float16* hr = hrg + pr * 131072;
    half8 af[16];
    #pragma unroll
    for (int kk = 0; kk < 16; ++kk) {
      union { half8 v; unsigned long long u[2]; } A;
      A.u[0] = __hip_atomic_load((const unsigned long long*)(hr + kk * 512),
                                 __ATOMIC_RELAXED, __HIP_MEMORY_SCOPE_AGENT);
      A.u[1] = __hip_atomic_load((const unsigned long long*)(hr + kk * 512) + 1,
                                 __ATOMIC_RELAXED, __HIP_MEMORY_SCOPE_AGENT);
      af[kk] = A.v;
    }
    float4v a0 = xga0, a1 = xga1;
    float4v b0v = (float4v){0.f,0.f,0.f,0.f}, b1v = b0v;
    #pragma unroll
    for (int kk = 0; kk < 8; ++kk) {
      a0 = __builtin_amdgcn_mfma_f32_16x16x32_f16(__builtin_bit_cast(half8, bw0[kk]), af[kk], a0, 0, 0, 0);
      a1 = __builtin_amdgcn_mfma_f32_16x16x32_f16(__builtin_bit_cast(half8, bw1[kk]), af[kk], a1, 0, 0, 0);
    }
    #pragma unroll
    for (int kk = 8; kk < 16; ++kk) {
      b0v = __builtin_amdgcn_mfma_f32_16x16x32_f16(__builtin_bit_cast(half8, bw0[kk]), af[kk], b0v, 0, 0, 0);
      b1v = __builtin_amdgcn_mfma_f32_16x16x32_f16(__builtin_bit_cast(half8, bw1[kk]), af[kk], b1v, 0, 0, 0);
    }
    a0 += b0v; a1 += b1v;
    float i0 = sigm(a0[0] + bq0[0]);
    float f0 = sigm(a0[1] + bq0[1]);
    float g0 = tanh_(a0[2] + bq0[2]);
    float o0 = sigm(a0[3] + bq0[3]);
    c0 = f0 * c0 + i0 * g0;
    float h0v = o0 * tanh_(c0);
    float i1 = sigm(a1[0] + bq1[0]);
    float f1 = sigm(a1[1] + bq1[1]);
    float g1 = tanh_(a1[2] + bq1[2]);
    float o1 = sigm(a1[3] + bq1[3]);
    c1 = f1 * c1 + i1 * g1;
    float h1v = o1 * tanh_(c1);
    unsigned int hb0 = (unsigned int)__builtin_bit_cast(unsigned short, (_Float16)h0v);
    unsigned int hb1 = (unsigned int)__builtin_bit_cast(unsigned short, (_Float16)h1v);
    unsigned int pb0 = __shfl_xor(hb0, 16);
    unsigned int pb1 = __shfl_xor(hb1, 16);
    unsigned int pair0 = hb0 | (pb0 << 16);
    unsigned int pair1 = hb1 | (pb1 << 16);
    unsigned int x0 = __shfl_xor(pair0, 32);
    unsigned int x1 = __shfl_xor(pair1, 32);
    if (q == 0) {
      int4v pk = {(int)pair0, (int)x0, (int)pair1, (int)x1};
      _Float16* dst = hw + (pr ^ 1) * 131072;
      asm volatile("global_store_dwordx4 %0, %1, off sc0 sc1"
                   :: "v"(dst), "v"(pk) : "memory");   // store-only asm
    }
    if (t == 511) {
      float part = h0v * wf0 + h1v * wf1;
      part += __shfl_xor(part, 16);
      part += __shfl_xor(part, 32);
      if (l < 16) {
        float v = part;
        if (s == 0 && w == 0) v += bfc[0];
        atomicAdd(out + g * 16 + l, v);
      }
    } else {
      asm volatile("s_waitcnt vmcnt(0)" ::: "memory");
      if (l == 0) {
        unsigned int old = atomicAdd(&wctr, 1u);
        if (old == 4u * (unsigned)t + 3u)
          __hip_atomic_store(fl + s * 16, (unsigned)(t + 1),
                             __ATOMIC_RELAXED, __HIP_MEMORY_SCOPE_AGENT);
      }
    }
    // tail: AFTER publish, off the critical path, overlapped with next poll.
    // x from regs (arrived: issued a full step ago), Wx from LDS (ds_read, pipelined).
    if (t < 511) {
      float4v n0 = (float4v){0.f,0.f,0.f,0.f}, n1 = n0;
      #pragma unroll
      for (int kk = 0; kk < 16; ++kk) {
        half8 wa0 = *(const half8*)&lwx[lb0 + kk * 512];
        half8 wa1 = *(const half8*)&lwx[lb1 + kk * 512];
        n0 = __builtin_amdgcn_mfma_f32_16x16x32_f16(wa0, __builtin_bit_cast(half8, xbr[kk]), n0, 0, 0, 0);
        n1 = __builtin_amdgcn_mfma_f32_16x16x32_f16(wa1, __builtin_bit_cast(half8, xbr[kk]), n1, 0, 0, 0);
      }
      xga0 = n0; xga1 = n1;
    }
  }
}

// ---------------------------------------------------------------- k_scan4 (FALLBACK, r15-proven)
__global__ __launch_bounds__(256, 1) void k_scan4(
    const _Float16* __restrict__ xg, const _Float16* __restrict__ wht,
    const float* __restrict__ wfc, const float* __restrict__ bfc,
    _Float16* __restrict__ hsl, unsigned int* __restrict__ flags,
    float* __restrict__ out)
{
  __shared__ unsigned int wctr;
  const int tid = threadIdx.x;
  if (tid == 0) wctr = 0;
  __syncthreads();

  const int w = tid >> 6, l = tid & 63;
  const int q = l >> 4;
  const int m = l & 15;
  const int bb = blockIdx.x;
  const int slot = bb >> 3;
  const int g = (bb & 7) * 2 + (slot >> 4);
  const int s = slot & 15;

  int4v bw0[16], bw1[16];
  {
    const _Float16* b0 = wht + ((long)(s * 128 + (2 * w + 0) * 16 + m)) * 512 + q * 8;
    const _Float16* b1 = wht + ((long)(s * 128 + (2 * w + 1) * 16 + m)) * 512 + q * 8;
    #pragma unroll
    for (int kk = 0; kk < 16; ++kk) {
      bw0[kk] = *(const int4v*)(b0 + kk * 32);
      bw1[kk] = *(const int4v*)(b1 + kk * 32);
    }
    #pragma unroll
    for (int kk = 0; kk < 16; ++kk)
      asm volatile("" : "+v"(bw0[kk]), "+v"(bw1[kk]));
  }

  float c0 = 0.f, c1 = 0.f;
  const int j0 = s * 32 + 8 * w + q;
  const int j1 = s * 32 + 8 * w + 4 + q;
  const float wf0 = wfc[j0], wf1 = wfc[j1];
  unsigned int* fl = flags + g * 256;
  const _Float16* xgr = xg + ((long)(g * 16 + m)) * 512 * 2048 + s * 128 + q * 4;
  const _Float16* hrg = hsl + (long)g * 8192 + q * 128 + m * 8;
  _Float16* hw = hsl + (long)(g * 16 + s) * 512 + w * 128 + m * 8;

  half4 xc0 = *(const half4*)(xgr + (2 * w + 0) * 16);
  half4 xc1 = *(const half4*)(xgr + (2 * w + 1) * 16);

  for (int t = 0; t < 512; ++t) {
    const int pr = t & 1;
    const long tn = (t < 511) ? (long)(t + 1) : 511L;
    const half4 xn0 = *(const half4*)(xgr + tn * 2048 + (2 * w + 0) * 16);
    const half4 xn1 = *(const half4*)(xgr + tn * 2048 + (2 * w + 1) * 16);
    if (t) {
      if (w == 0 && l < 16 && l != s) {
        unsigned int* p = fl + l * 16;
        while (__hip_atomic_load(p, __ATOMIC_RELAXED, __HIP_MEMORY_SCOPE_AGENT)
               < (unsigned)t) {}
      }
      asm volatile("" ::: "memory");
      __syncthreads();
    }
    const _Float16* hr = hrg + pr * 131072;
    int4v av[16];
    #pragma unroll
    for (int kk = 0; kk < 16; ++kk)
      asm volatile("global_load_dwordx4 %0, %1, off sc0 sc1"
                   : "=&v"(av[kk]) : "v"(hr + kk * 512) : "memory");
    asm volatile("s_waitcnt vmcnt(0)" ::: "memory");
    __builtin_amdgcn_sched_barrier(0);

    float4v a0 = (float4v){0.f,0.f,0.f,0.f}, a1 = a0, b0v = a0, b1v = a0;
    #pragma unroll
    for (int kk = 0; kk < 8; ++kk) {
      a0 = __builtin_amdgcn_mfma_f32_16x16x32_f16(__builtin_bit_cast(half8, bw0[kk]),
                                                  __builtin_bit_cast(half8, av[kk]), a0, 0, 0, 0);
      a1 = __builtin_amdgcn_mfma_f32_16x16x32_f16(__builtin_bit_cast(half8, bw1[kk]),
                                                  __builtin_bit_cast(half8, av[kk]), a1, 0, 0, 0);
    }
    #pragma unroll
    for (int kk = 8; kk < 16; ++kk) {
      b0v = __builtin_amdgcn_mfma_f32_16x16x32_f16(__builtin_bit_cast(half8, bw0[kk]),
                                                   __builtin_bit_cast(half8, av[kk]), b0v, 0, 0, 0);
      b1v = __builtin_amdgcn_mfma_f32_16x16x32_f16(__builtin_bit_cast(half8, bw1[kk]),
                                                   __builtin_bit_cast(half8, av[kk]), b1v, 0, 0, 0);
    }
    a0 += b0v; a1 += b1v;
    float i0 = sigm(a0[0] + (float)xc0[0]);
    float f0 = sigm(a0[1] + (float)xc0[1]);
    float g0 = tanh_(a0[2] + (float)xc0[2]);
    float o0 = sigm(a0[3] + (float)xc0[3]);
    c0 = f0 * c0 + i0 * g0;
    float h0v = o0 * tanh_(c0);
    float i1 = sigm(a1[0] + (float)xc1[0]);
    float f1 = sigm(a1[1] + (float)xc1[1]);
    float g1 = tanh_(a1[2] + (float)xc1[2]);
    float o1 = sigm(a1[3] + (float)xc1[3]);
    c1 = f1 * c1 + i1 * g1;
    float h1v = o1 * tanh_(c1);
    unsigned int hb0 = (unsigned int)__builtin_bit_cast(unsigned short, (_Float16)h0v);
    unsigned int hb1 = (unsigned int)__builtin_bit_cast(unsigned short, (_Float16)h1v);
    unsigned int pb0 = __shfl_xor(hb0, 16);
    unsigned int pb1 = __shfl_xor(hb1, 16);
    unsigned int pair0 = hb0 | (pb0 << 16);
    unsigned int pair1 = hb1 | (pb1 << 16);
    unsigned int x0 = __shfl_xor(pair0, 32);
    unsigned int x1 = __shfl_xor(pair1, 32);
    if (q == 0) {
      int4v pk = {(int)pair0, (int)x0, (int)pair1, (int)x1};
      _Float16* dst = hw + (pr ^ 1) * 131072;
      asm volatile("global_store_dwordx4 %0, %1, off sc0 sc1"
                   :: "v"(dst), "v"(pk) : "memory");
    }
    if (t == 511) {
      float part = h0v * wf0 + h1v * wf1;
      part += __shfl_xor(part, 16);
      part += __shfl_xor(part, 32);
      if (l < 16) {
        float v = part;
        if (s == 0 && w == 0) v += bfc[0];
        atomicAdd(out + g * 16 + l, v);
      }
    } else {
      asm volatile("s_waitcnt vmcnt(0)" ::: "memory");
      if (l == 0) {
        unsigned int old = atomicAdd(&wctr, 1u);
        if (old == 4u * (unsigned)t + 3u)
          __hip_atomic_store(fl + s * 16, (unsigned)(t + 1),
                             __ATOMIC_RELAXED, __HIP_MEMORY_SCOPE_AGENT);
      }
    }
    xc0 = xn0; xc1 = xn1;
  }
}

// ---------------------------------------------------------------- launch
extern "C" void kernel_launch(void* const* d_in, const int* in_sizes, int n_in,
                              void* d_out, int out_size, void* d_ws, size_t ws_size,
                              hipStream_t stream)
{
  const float* x   = (const float*)d_in[0];
  const float* Wx  = (const float*)d_in[1];
  const float* Wh  = (const float*)d_in[2];
  const float* b   = (const float*)d_in[3];
  const float* Wfc = (const float*)d_in[4];
  const float* bfc = (const float*)d_in[5];
  char* ws = (char*)d_ws;

  const size_t OFF_XG  = 0;                          // f16 [131072][2048] = 512MB (fallback)
  const size_t OFF_XB  = 536870912UL;                // f16 x          = 128MB
  const size_t OFF_WXT = OFF_XB + 134217728UL;       // f16 [2048][512] = 2MB
  const size_t OFF_WHT = OFF_WXT + 2097152UL;        // f16 [2048][512] = 2MB
  const size_t OFF_BP  = OFF_WHT + 2097152UL;        // f32 [2048]
  const size_t OFF_H   = OFF_BP + 8192UL;            // f16 [2][256][512] = 512KB
  const size_t OFF_FL  = OFF_H + 524288UL;           // u32 flags, 64B apart = 16KB
  const size_t NEED    = OFF_FL + 16384UL;
  if (ws_size < NEED) return;

  _Float16* xgp = (_Float16*)(ws + OFF_XG);
  _Float16* xfp = (_Float16*)(ws + OFF_XB);
  _Float16* wxt = (_Float16*)(ws + OFF_WXT);
  _Float16* wht = (_Float16*)(ws + OFF_WHT);
  float*    bp  = (float*)(ws + OFF_BP);
  _Float16* hsl = (_Float16*)(ws + OFF_H);
  unsigned int* flg = (unsigned int*)(ws + OFF_FL);
  float* outp = (float*)d_out;

  hipMemsetAsync(ws + OFF_H, 0, 262144, stream);     // h_0 = 0 (parity-0 buffer)
  hipMemsetAsync(ws + OFF_FL, 0, 16384, stream);     // publish counters = 0
  hipMemsetAsync(d_out, 0, sizeof(float) * 256, stream);

  k_prep<<<2048, 256, 0, stream>>>(x, b, xfp, bp);
  k_wtr<<<256, 256, 0, stream>>>(Wx, wxt);
  k_wtr<<<256, 256, 0, stream>>>(Wh, wht);

  const _Float16* xfc = xfp;
  const _Float16* whtc = wht;
  const _Float16* wxtc = wxt;
  const float* bpc = bp;
  void* argsF[] = { (void*)&xfc, (void*)&whtc, (void*)&wxtc, (void*)&bpc,
                    (void*)&Wfc, (void*)&bfc, (void*)&hsl, (void*)&flg, (void*)&outp };
  hipError_t rcA = hipFuncSetAttribute((const void*)k_scanf2,
                                       hipFuncAttributeMaxDynamicSharedMemorySize,
                                       131072);
  hipError_t rcL = hipErrorUnknown;
  if (rcA == hipSuccess)
    rcL = hipLaunchCooperativeKernel((void*)k_scanf2, dim3(256), dim3(256),
                                     argsF, 131072, stream);
  if (rcL != hipSuccess) {
    (void)hipGetLastError();  // clear sticky error; proven split path
    k_gemm_xg<<<16384, 256, 0, stream>>>(xfp, wxt, bp, xgp);
    const _Float16* xgc = xgp;
    void* args4[] = { (void*)&xgc, (void*)&whtc, (void*)&Wfc, (void*)&bfc,
                      (void*)&hsl, (void*)&flg, (void*)&outp };
    hipLaunchCooperativeKernel((void*)k_scan4, dim3(256), dim3(256), args4, 0, stream);
  }
}